// Round 1
// 142.737 us; speedup vs baseline: 1.0685x; 1.0685x over previous
//
#include <hip/hip_runtime.h>

// z(8,128,64,64) f32, codes(16,256,8) f32
// out: soft(8,64,64,128) | hard(8,64,64,128) | idx(8,64,64,16) as f32
#define NPOS 32768
#define CCH  128
#define LL   16
#define KK   256
#define CD   8

typedef float f32x2 __attribute__((ext_vector_type(2)));

#if __has_builtin(__builtin_amdgcn_exp2f)
#define EXP2NEG(x) __builtin_amdgcn_exp2f(-(x))
#else
#define EXP2NEG(x) __expf(-0.6931471805599453f * (x))
#endif

// F = sqrt(2)*log2(e): with hv' = F*hv, c' = F*c,
//   dot = -0.5*|hv'|^2 - 0.5*|c'|^2 + hv'.c' = -(log2e * dist)^2
//   => exp2(-sqrt(-dot)) == exp(-dist)  (correct softmin temperature 1.0)
#define FS    2.0402788939f
#define INVFS 0.4901290717f   // ln2/sqrt(2) == 1/FS exactly

__global__ __launch_bounds__(512) void soft_hard_enc(
    const float* __restrict__ z, const float* __restrict__ codes,
    float* __restrict__ out)
{
    // 4 latents x 128 pairs x 16 floats: [e_c0,o_c0,e_c1,o_c1,...] scaled by FS
    __shared__ float s_codes[4 * 2048];   // 32 KB
    __shared__ f32x2 s_c2h[4 * 128];      // 4 KB: per pair {-0.5|c'|^2 even, -0.5|c'|^2 odd}

    const int tid = (int)threadIdx.x;
    const int bid = (int)blockIdx.x;
    const int posBase = (bid >> 2) * 128;
    const int lBase   = (bid & 3) * 4;

    // ---- one-time: stage codes pair-interleaved + scaled, plus -0.5*|c'|^2 per pair
    {
        const int ll = tid >> 7;          // 0..3
        const int j  = tid & 127;         // pair index
        const float* g = codes + ((size_t)((lBase + ll) * KK + 2 * j)) * CD;
        float4 q0 = *(const float4*)(g + 0);   // even code c0..c3
        float4 q1 = *(const float4*)(g + 4);   // even c4..c7
        float4 q2 = *(const float4*)(g + 8);   // odd  c0..c3
        float4 q3 = *(const float4*)(g + 12);  // odd  c4..c7
        q0.x *= FS; q0.y *= FS; q0.z *= FS; q0.w *= FS;
        q1.x *= FS; q1.y *= FS; q1.z *= FS; q1.w *= FS;
        q2.x *= FS; q2.y *= FS; q2.z *= FS; q2.w *= FS;
        q3.x *= FS; q3.y *= FS; q3.z *= FS; q3.w *= FS;
        float* d = s_codes + ll * 2048 + j * 16;
        ((float4*)d)[0] = (float4){q0.x, q2.x, q0.y, q2.y};
        ((float4*)d)[1] = (float4){q0.z, q2.z, q0.w, q2.w};
        ((float4*)d)[2] = (float4){q1.x, q3.x, q1.y, q3.y};
        ((float4*)d)[3] = (float4){q1.z, q3.z, q1.w, q3.w};
        float c2e = q0.x*q0.x + q0.y*q0.y + q0.z*q0.z + q0.w*q0.w
                  + q1.x*q1.x + q1.y*q1.y + q1.z*q1.z + q1.w*q1.w;
        float c2o = q2.x*q2.x + q2.y*q2.y + q2.z*q2.z + q2.w*q2.w
                  + q3.x*q3.x + q3.y*q3.y + q3.z*q3.z + q3.w*q3.w;
        s_c2h[ll * 128 + j] = (f32x2){-0.5f * c2e, -0.5f * c2o};
    }

    const int l   = tid >> 7;             // wave-uniform latent (2 waves per l)
    const int p   = tid & 127;
    const int pos = posBase + p;
    const int b   = pos >> 12;
    const int wh  = pos & 4095;
    const int l4  = lBase + l;

    // hv load (coalesced per channel), scaled, broadcast into pairs; -0.5*|hv'|^2
    const float* zp = z + (((size_t)(b * CCH + l4 * CD)) << 12) + wh;
    f32x2 hvp[CD];
    float hv2 = 0.f;
#pragma unroll
    for (int c = 0; c < CD; ++c) {
        float v = FS * zp[((size_t)c) << 12];
        hvp[c] = (f32x2){v, v};
        hv2 = __builtin_fmaf(v, v, hv2);
    }
    const f32x2 hv2b = (f32x2){-0.5f * hv2, -0.5f * hv2};

    __syncthreads();

    const float4* cb  = (const float4*)(s_codes + l * 2048);
    const f32x2*  c2b = &s_c2h[l * 128];

    f32x2 acc[CD];
#pragma unroll
    for (int c = 0; c < CD; ++c) acc[c] = (f32x2){0.f, 0.f};
    f32x2 ssump = (f32x2){0.f, 0.f};
    float bd0 = -3.4e38f, bd1 = -3.4e38f;   // track MAX of dot (== min d2)
    int   bj0 = 0,        bj1 = 0;

#pragma unroll 4
    for (int j = 0; j < KK / 2; ++j) {
        float4 q0 = cb[j * 4 + 0];     // wave-uniform addr -> LDS broadcast
        float4 q1 = cb[j * 4 + 1];
        float4 q2 = cb[j * 4 + 2];
        float4 q3 = cb[j * 4 + 3];
        f32x2 cp[CD] = {
            {q0.x, q0.y}, {q0.z, q0.w}, {q1.x, q1.y}, {q1.z, q1.w},
            {q2.x, q2.y}, {q2.z, q2.w}, {q3.x, q3.y}, {q3.z, q3.w}};

        f32x2 dotp = c2b[j] + hv2b;    // seed with -(|hv'|^2+|c'|^2)/2
#pragma unroll
        for (int c = 0; c < CD; ++c)
            dotp = __builtin_elementwise_fma(hvp[c], cp[c], dotp);
        // dotp = -(log2e*dist)^2  (<= 0 up to rounding); clamp guards sqrt(NaN)
        f32x2 dm = __builtin_elementwise_min(dotp, (f32x2){0.f, 0.f});
        float s0 = __builtin_amdgcn_sqrtf(-dm[0]);   // free neg input modifier
        float s1 = __builtin_amdgcn_sqrtf(-dm[1]);
        float e0 = EXP2NEG(s0);                      // = exp(-dist) exactly
        float e1 = EXP2NEG(s1);
        f32x2 ep = (f32x2){e0, e1};
        ssump += ep;
#pragma unroll
        for (int c = 0; c < CD; ++c)
            acc[c] = __builtin_elementwise_fma(ep, cp[c], acc[c]);

        // per-parity argmax(dot) = argmin(d2); strict > keeps first occurrence
        if (dotp[0] > bd0) { bd0 = dotp[0]; bj0 = j; }
        if (dotp[1] > bd1) { bd1 = dotp[1]; bj1 = j; }
    }

    // merge parities; exact-tie -> smaller k (np.argmin first occurrence)
    int ke = 2 * bj0, ko = 2 * bj1 + 1;
    int bestk = ke;
    if (bd1 > bd0 || (bd1 == bd0 && ko < ke)) bestk = ko;

    const float ssum = ssump[0] + ssump[1];
    const float sc   = INVFS / ssum;    // un-scale codes + softmax normalize

    float a0 = (acc[0][0] + acc[0][1]) * sc;
    float a1 = (acc[1][0] + acc[1][1]) * sc;
    float a2 = (acc[2][0] + acc[2][1]) * sc;
    float a3 = (acc[3][0] + acc[3][1]) * sc;
    float a4 = (acc[4][0] + acc[4][1]) * sc;
    float a5 = (acc[5][0] + acc[5][1]) * sc;
    float a6 = (acc[6][0] + acc[6][1]) * sc;
    float a7 = (acc[7][0] + acc[7][1]) * sc;

    const size_t obase = (size_t)pos * CCH + (size_t)(l4 * CD);
    *(float4*)&out[obase]     = (float4){a0, a1, a2, a3};
    *(float4*)&out[obase + 4] = (float4){a4, a5, a6, a7};

    // hard: gather un-scaled code from global (L2-hot 128 KB)
    const float* hp = codes + ((size_t)(l4 * KK + bestk)) * CD;
    float4 h0 = *(const float4*)(hp + 0);
    float4 h1 = *(const float4*)(hp + 4);
    float* outh = out + (size_t)NPOS * CCH;
    *(float4*)&outh[obase]     = h0;
    *(float4*)&outh[obase + 4] = h1;

    float* outi = out + (size_t)2 * NPOS * CCH;
    outi[(size_t)pos * LL + l4] = (float)bestk;
}

extern "C" void kernel_launch(void* const* d_in, const int* in_sizes, int n_in,
                              void* d_out, int out_size, void* d_ws, size_t ws_size,
                              hipStream_t stream) {
    const float* z     = (const float*)d_in[0];
    const float* codes = (const float*)d_in[1];
    float* out = (float*)d_out;
    soft_hard_enc<<<dim3((NPOS / 128) * 4), dim3(512), 0, stream>>>(z, codes, out);
}